// Round 1
// baseline (1523.746 us; speedup 1.0000x reference)
//
#include <hip/hip_runtime.h>

// out[o,c,y,x] = sum_{i,j in [0,31)} signal[c, y+i-15, x+j-15] * w[o,c,i,j] + bias[c]
// (cross-correlation, no flip; bias indexed by c — reference broadcasts (1,8)x(8,8))

#define TX 64
#define TY 32
#define SW 94          // TX + 30
#define SH 62          // TY + 30
#define SROW 97        // odd LDS row stride (floats) -> <=2-way bank aliasing (free)

// weights transposed to [c][i][j][o] so the 8 o-values for a (c,i,j) are
// 8 consecutive floats at a block-uniform address -> scalar loads.
__device__ float g_wtr[8 * 31 * 31 * 8];   // 246 KB

__global__ void wtranspose(const float* __restrict__ wgt) {
  int t = blockIdx.x * 256 + threadIdx.x;
  if (t >= 8 * 961 * 8) return;
  const int o  = t & 7;
  const int r  = t >> 3;        // c*961 + ij
  const int c  = r / 961;
  const int ij = r - c * 961;
  g_wtr[t] = wgt[(o * 8 + c) * 961 + ij];
}

__global__ __launch_bounds__(256, 4)
void fftconv_direct(const float* __restrict__ sig,
                    const float* __restrict__ bias,
                    float* __restrict__ out) {
  __shared__ float slds[SH * SROW + 8];

  const int tid = threadIdx.x;
  const int c  = blockIdx.z;
  const int x0 = blockIdx.x * TX;
  const int y0 = blockIdx.y * TY;

  // stage padded signal tile: slds[r][cc] = signal[c, y0+r-15, x0+cc-15] (0 if OOB)
  const float* sc = sig + c * (1024 * 1024);
  for (int f = tid; f < SH * SW; f += 256) {
    const int r  = f / SW;
    const int cc = f - r * SW;
    const int gy = y0 + r - 15;
    const int gx = x0 + cc - 15;
    float v = 0.f;
    if ((unsigned)gy < 1024u && (unsigned)gx < 1024u) v = sc[gy * 1024 + gx];
    slds[r * SROW + cc] = v;
  }
  __syncthreads();

  const int txg = tid & 7;      // 8 x-groups of 8 pixels
  const int ty  = tid >> 3;     // 32 y rows

  float acc[8][8];              // [o][p]
  #pragma unroll
  for (int o = 0; o < 8; ++o)
    #pragma unroll
    for (int p = 0; p < 8; ++p) acc[o][p] = 0.f;

  const float* wcb = &g_wtr[c * 961 * 8];

  for (int i = 0; i < 31; ++i) {
    const float* srow = &slds[(ty + i) * SROW + txg * 8];
    const float* wrow = &wcb[i * 31 * 8];
    float win[8];
    #pragma unroll
    for (int p = 0; p < 8; ++p) win[p] = srow[p];
    #pragma unroll
    for (int j = 0; j < 31; ++j) {
      if (j) {
        #pragma unroll
        for (int p = 0; p < 7; ++p) win[p] = win[p + 1];
        win[7] = srow[7 + j];
      }
      // 8 o-weights: block-uniform, consecutive -> s_load_dwordx4 x2
      const float4 wa = *(const float4*)(wrow + j * 8);
      const float4 wb = *(const float4*)(wrow + j * 8 + 4);
      const float wv[8] = {wa.x, wa.y, wa.z, wa.w, wb.x, wb.y, wb.z, wb.w};
      #pragma unroll
      for (int o = 0; o < 8; ++o) {
        #pragma unroll
        for (int p = 0; p < 8; ++p)
          acc[o][p] = fmaf(win[p], wv[o], acc[o][p]);
      }
    }
  }

  const float bv = bias[c];
  const int y  = y0 + ty;
  const int xb = x0 + txg * 8;
  #pragma unroll
  for (int o = 0; o < 8; ++o) {
    float4 v0, v1;
    v0.x = acc[o][0] + bv; v0.y = acc[o][1] + bv;
    v0.z = acc[o][2] + bv; v0.w = acc[o][3] + bv;
    v1.x = acc[o][4] + bv; v1.y = acc[o][5] + bv;
    v1.z = acc[o][6] + bv; v1.w = acc[o][7] + bv;
    float* op = out + (((size_t)(o * 8 + c) * 1024 + y) * 1024 + xb);
    *(float4*)(op)     = v0;
    *(float4*)(op + 4) = v1;
  }
}

extern "C" void kernel_launch(void* const* d_in, const int* in_sizes, int n_in,
                              void* d_out, int out_size, void* d_ws, size_t ws_size,
                              hipStream_t stream) {
  const float* sig  = (const float*)d_in[0];   // (1,8,1024,1024) fp32
  const float* wgt  = (const float*)d_in[1];   // (8,8,31,31) fp32
  const float* bias = (const float*)d_in[2];   // (8,) fp32
  float* out = (float*)d_out;                  // (8,8,1024,1024) fp32

  wtranspose<<<(8 * 961 * 8 + 255) / 256, 256, 0, stream>>>(wgt);
  dim3 grid(1024 / TX, 1024 / TY, 8);
  fftconv_direct<<<grid, 256, 0, stream>>>(sig, bias, out);
}

// Round 2
// 1154.138 us; speedup vs baseline: 1.3202x; 1.3202x over previous
//
#include <hip/hip_runtime.h>

// out[o,c,y,x] = sum_{i,j in [0,31)} signal[c, y+i-15, x+j-15] * w[o,c,i,j] + bias[c]
// Compute via v_dot2_f32_f16: 2 f16 MACs (over j-pairs) with fp32 accumulate per inst.

#define TX 64
#define TY 32
#define SH 62          // TY + 30 rows
#define NDW 48         // packed f16-pair dwords per row (covers elements 0..96)
#define SROW 49        // LDS row stride in dwords (odd -> 2-way bank aliasing = free)

typedef _Float16 half2v __attribute__((ext_vector_type(2)));

// weights packed as half2 (w[o,c,i,2jp], w[o,c,i,2jp+1]) laid out [c][i][jp][o]
// -> the 8 o-values for one (c,i,jp) are 8 consecutive dwords at a block-uniform
// address -> scalar loads.
__device__ unsigned int g_wtr2[8 * 31 * 16 * 8];   // 127 KB

__global__ void wtranspose(const float* __restrict__ wgt) {
  int t = blockIdx.x * 256 + threadIdx.x;
  if (t >= 8 * 31 * 16 * 8) return;
  const int o  = t & 7;
  int r        = t >> 3;
  const int jp = r & 15;  r >>= 4;
  const int i  = r % 31;
  const int c  = r / 31;
  const int j0 = 2 * jp;
  const float w0 = wgt[((o * 8 + c) * 31 + i) * 31 + j0];
  const float w1 = (j0 + 1 < 31) ? wgt[((o * 8 + c) * 31 + i) * 31 + j0 + 1] : 0.f;
  half2v h; h.x = (_Float16)w0; h.y = (_Float16)w1;
  g_wtr2[((c * 31 + i) * 16 + jp) * 8 + o] = __builtin_bit_cast(unsigned int, h);
}

__global__ __launch_bounds__(256, 4)
void fftconv_dot2(const float* __restrict__ sig,
                  const float* __restrict__ bias,
                  float* __restrict__ out) {
  // copy0: dword d = (s[2d], s[2d+1]); copy1: dword d = (s[2d+1], s[2d+2])
  __shared__ unsigned int lds0[SH * SROW];
  __shared__ unsigned int lds1[SH * SROW];

  const int tid = threadIdx.x;
  const int c  = blockIdx.z;
  const int x0 = blockIdx.x * TX;
  const int y0 = blockIdx.y * TY;

  const float* sc = sig + c * (1024 * 1024);
  for (int f = tid; f < SH * NDW; f += 256) {
    const int r = f / NDW;
    const int d = f - r * NDW;
    const int gy = y0 + r - 15;
    const int gx = x0 + 2 * d - 15;
    float s0 = 0.f, s1 = 0.f, s2 = 0.f;
    if ((unsigned)gy < 1024u) {
      const float* srcr = sc + gy * 1024;
      if ((unsigned)gx < 1024u)       s0 = srcr[gx];
      if ((unsigned)(gx + 1) < 1024u) s1 = srcr[gx + 1];
      if ((unsigned)(gx + 2) < 1024u) s2 = srcr[gx + 2];
    }
    half2v h0; h0.x = (_Float16)s0; h0.y = (_Float16)s1;
    half2v h1; h1.x = (_Float16)s1; h1.y = (_Float16)s2;
    lds0[r * SROW + d] = __builtin_bit_cast(unsigned int, h0);
    lds1[r * SROW + d] = __builtin_bit_cast(unsigned int, h1);
  }
  __syncthreads();

  const int txg = tid & 7;      // 8 x-groups of 8 pixels
  const int ty  = tid >> 3;     // 32 y rows

  float acc[8][8];              // [o][p]
  #pragma unroll
  for (int o = 0; o < 8; ++o)
    #pragma unroll
    for (int p = 0; p < 8; ++p) acc[o][p] = 0.f;

  for (int i = 0; i < 31; ++i) {
    const unsigned int* row0 = &lds0[(ty + i) * SROW + txg * 4];
    const unsigned int* row1 = &lds1[(ty + i) * SROW + txg * 4];
    const unsigned int* wrow = &g_wtr2[(c * 31 + i) * 16 * 8];

    // rolling windows: at iteration jp, we[q] = row0[jp+q], wo[q] = row1[jp+q]
    unsigned int we[4], wo[4];
    #pragma unroll
    for (int q = 0; q < 4; ++q) { we[q] = row0[q]; wo[q] = row1[q]; }

    #pragma unroll
    for (int jp = 0; jp < 16; ++jp) {
      // 8 o-weights for this (i,jp): block-uniform, consecutive -> s_load
      const uint4 wa = *(const uint4*)(wrow + jp * 8);
      const uint4 wb = *(const uint4*)(wrow + jp * 8 + 4);
      const unsigned int wv[8] = {wa.x, wa.y, wa.z, wa.w, wb.x, wb.y, wb.z, wb.w};
      #pragma unroll
      for (int o = 0; o < 8; ++o) {
        const half2v wh = __builtin_bit_cast(half2v, wv[o]);
        #pragma unroll
        for (int p = 0; p < 8; ++p) {
          const unsigned int su = (p & 1) ? wo[(p - 1) >> 1] : we[p >> 1];
          acc[o][p] = __builtin_amdgcn_fdot2(__builtin_bit_cast(half2v, su), wh,
                                             acc[o][p], false);
        }
      }
      if (jp < 15) {
        #pragma unroll
        for (int q = 0; q < 3; ++q) { we[q] = we[q + 1]; wo[q] = wo[q + 1]; }
        we[3] = row0[jp + 4];
        wo[3] = row1[jp + 4];
      }
    }
  }

  const float bv = bias[c];
  const int y  = y0 + ty;
  const int xb = x0 + txg * 8;
  #pragma unroll
  for (int o = 0; o < 8; ++o) {
    float4 v0, v1;
    v0.x = acc[o][0] + bv; v0.y = acc[o][1] + bv;
    v0.z = acc[o][2] + bv; v0.w = acc[o][3] + bv;
    v1.x = acc[o][4] + bv; v1.y = acc[o][5] + bv;
    v1.z = acc[o][6] + bv; v1.w = acc[o][7] + bv;
    float* op = out + (((size_t)(o * 8 + c) * 1024 + y) * 1024 + xb);
    *(float4*)(op)     = v0;
    *(float4*)(op + 4) = v1;
  }
}

extern "C" void kernel_launch(void* const* d_in, const int* in_sizes, int n_in,
                              void* d_out, int out_size, void* d_ws, size_t ws_size,
                              hipStream_t stream) {
  const float* sig  = (const float*)d_in[0];   // (1,8,1024,1024) fp32
  const float* wgt  = (const float*)d_in[1];   // (8,8,31,31) fp32
  const float* bias = (const float*)d_in[2];   // (8,) fp32
  float* out = (float*)d_out;                  // (8,8,1024,1024) fp32

  wtranspose<<<(8 * 31 * 16 * 8 + 255) / 256, 256, 0, stream>>>(wgt);
  dim3 grid(1024 / TX, 1024 / TY, 8);
  fftconv_dot2<<<grid, 256, 0, stream>>>(sig, bias, out);
}